// Round 3
// baseline (2653.756 us; speedup 1.0000x reference)
//
#include <hip/hip_runtime.h>
#include <hip/hip_cooperative_groups.h>
#include <cmath>

#define BATCH 64
#define SEQL  32
#define EMBD  300
#define HIDD  500
#define NOBJ  64
#define GHID  100
#define ANSN  1000
#define MCOL  2048   // t*64+b column dimension

// LSTM v3 partition
#define UBLK 10      // unit-blocks per group
#define GRPS 16      // batch groups (4 rows each)
#define UPB  50      // units per block
#define KC   64      // k chunk
#define KPAD 68      // ws row stride (16B-aligned, 2-way banks)
#define HPAD 520     // hs row stride (16B-aligned)

__device__ __forceinline__ float sigmf(float x){ return 1.f/(1.f+expf(-x)); }

// ---------------- embT[k][t*64+b] = table[sent[b*32+t]][k] ----------------
__global__ void k_embT(const int* __restrict__ sent, const float* __restrict__ table,
                       float* __restrict__ embT)
{
    __shared__ float T[64][101];
    int t  = blockIdx.y;
    int k0 = blockIdx.x * 100;
    int tid = threadIdx.x;
    for (int i = tid; i < 64*100; i += 256){
        int b = i / 100, k = i - b*100;
        T[b][k] = table[(size_t)sent[b*SEQL + t]*EMBD + k0 + k];
    }
    __syncthreads();
    for (int i = tid; i < 100*64; i += 256){
        int k = i >> 6, b = i & 63;
        embT[(size_t)(k0+k)*MCOL + t*64 + b] = T[b][k];
    }
}

// ---------------- NN GEMM: C[n][m] = sum_k A[n][k]*B[k][m] + bias0[n]+bias1[n] ----------------
__global__ __launch_bounds__(256) void k_gemm_nn(const float* __restrict__ A, const float* __restrict__ B,
                 const float* __restrict__ bias0, const float* __restrict__ bias1,
                 float* __restrict__ C, int N, int M, int K)
{
    __shared__ float As[16][65];
    __shared__ float Bs[16][65];
    int n0 = blockIdx.y*64, m0 = blockIdx.x*64;
    int tid = threadIdx.x, tx = tid & 15, ty = tid >> 4;
    float acc[4][4] = {};
    for (int k0 = 0; k0 < K; k0 += 16){
        for (int i = tid; i < 64*16; i += 256){
            int n = i >> 4, k = i & 15;
            As[k][n] = (n0+n < N && k0+k < K) ? A[(size_t)(n0+n)*K + k0+k] : 0.f;
        }
        for (int i = tid; i < 16*64; i += 256){
            int k = i >> 6, m = i & 63;
            Bs[k][m] = (k0+k < K) ? B[(size_t)(k0+k)*M + m0+m] : 0.f;
        }
        __syncthreads();
        #pragma unroll
        for (int kk = 0; kk < 16; ++kk){
            float a[4], b[4];
            #pragma unroll
            for (int i=0;i<4;i++) a[i] = As[kk][ty*4+i];
            #pragma unroll
            for (int j=0;j<4;j++) b[j] = Bs[kk][tx*4+j];
            #pragma unroll
            for (int i=0;i<4;i++)
                #pragma unroll
                for (int j=0;j<4;j++) acc[i][j] += a[i]*b[j];
        }
        __syncthreads();
    }
    #pragma unroll
    for (int i=0;i<4;i++){
        int n = n0 + ty*4 + i;
        if (n >= N) continue;
        float bsum = bias0[n] + bias1[n];
        float4 v;
        v.x = acc[i][0]+bsum; v.y = acc[i][1]+bsum; v.z = acc[i][2]+bsum; v.w = acc[i][3]+bsum;
        *(float4*)(C + (size_t)n*M + m0 + tx*4) = v;
    }
}

// ---------------- LSTM v3: 160 blocks = 16 batch-groups x 10 unit-blocks ----------------
// hW layout: [buf][g][k 0..511][b 0..3]; h(t) written to buf t&1, h(-1) in buf 1.
// Group barrier: monotonic counter per group, release-add / acquire-load, AGENT scope.
__global__ __launch_bounds__(256, 1) void k_lstm_v3(float* __restrict__ hW,
    const float* __restrict__ xgT, const float* __restrict__ Whh,
    const float* __restrict__ h0, const float* __restrict__ c0,
    const int* __restrict__ lens, int* __restrict__ bar)
{
    __shared__ float ws[200*KPAD];   // 54.4 KB: W slice, rows = gate*50+ul
    __shared__ float hs[4*HPAD];     // 8.3 KB: h, [b][k]
    int tid = threadIdx.x;
    int bid = blockIdx.x;
    int g = bid / UBLK, u = bid - g*UBLK;
    int u0 = u * UPB;
    int b0 = g * 4;
    int u_l = tid >> 2, b = tid & 3;
    bool act = (u_l < UPB);
    int* mybar = bar + g*32;         // 128B-padded counters

    float c = 0.f, hprev = 0.f; int mylen = 0;
    if (act){
        int bg = b0 + b, uu = u0 + u_l;
        c = c0[bg*HIDD + uu];
        hprev = h0[bg*HIDD + uu];
        mylen = lens[bg];
        hW[((size_t)(1*GRPS + g)*512 + uu)*4 + b] = hprev;   // h(-1) -> buf1
    }
    if (u == 0 && tid < 96){         // zero pad rows 500..511, both buffers
        int kk = 500 + (tid >> 3);
        int r  = tid & 7;
        hW[((size_t)((r&1)*GRPS + g)*512 + kk)*4 + (r>>1)] = 0.f;
    }
    // init barrier
    __syncthreads();
    if (tid == 0){
        __hip_atomic_fetch_add(mybar, 1, __ATOMIC_RELEASE, __HIP_MEMORY_SCOPE_AGENT);
        while (__hip_atomic_load(mybar, __ATOMIC_RELAXED, __HIP_MEMORY_SCOPE_AGENT) < UBLK)
            __builtin_amdgcn_s_sleep(1);
        (void)__hip_atomic_load(mybar, __ATOMIC_ACQUIRE, __HIP_MEMORY_SCOPE_AGENT);
    }
    __syncthreads();

    for (int t = 0; t < SEQL; ++t){
        const float* hr = hW + (size_t)(((t&1)^1)*GRPS + g)*512*4;
        for (int i = tid; i < 2048; i += 256){       // stage h (full K) once per step
            int k = i >> 2, bb = i & 3;
            hs[bb*HPAD + k] = hr[i];
        }
        float acc0=0.f, acc1=0.f, acc2=0.f, acc3=0.f;
        for (int ch = 0; ch < 8; ++ch){
            int k0 = ch*KC;
            __syncthreads();                          // ws reuse guard (also covers hs stage at ch=0)
            for (int i = tid; i < 200*KC; i += 256){  // stage W chunk, coalesced along k
                int row = i >> 6, kk = i & 63;
                int gate = row / UPB;
                int ul2  = row - gate*UPB;
                int k = k0 + kk;
                ws[row*KPAD + kk] = (k < HIDD) ?
                    Whh[(size_t)(gate*HIDD + u0 + ul2)*HIDD + k] : 0.f;
            }
            __syncthreads();
            if (act){
                #pragma unroll
                for (int kk4 = 0; kk4 < KC/4; ++kk4){
                    float4 hv = *(const float4*)&hs[b*HPAD + k0 + kk4*4];
                    float4 w0 = *(const float4*)&ws[(0*UPB + u_l)*KPAD + kk4*4];
                    float4 w1 = *(const float4*)&ws[(1*UPB + u_l)*KPAD + kk4*4];
                    float4 w2 = *(const float4*)&ws[(2*UPB + u_l)*KPAD + kk4*4];
                    float4 w3 = *(const float4*)&ws[(3*UPB + u_l)*KPAD + kk4*4];
                    acc0 += w0.x*hv.x + w0.y*hv.y + w0.z*hv.z + w0.w*hv.w;
                    acc1 += w1.x*hv.x + w1.y*hv.y + w1.z*hv.z + w1.w*hv.w;
                    acc2 += w2.x*hv.x + w2.y*hv.y + w2.z*hv.z + w2.w*hv.w;
                    acc3 += w3.x*hv.x + w3.y*hv.y + w3.z*hv.z + w3.w*hv.w;
                }
            }
        }
        if (act){
            int uu = u0 + u_l, bg = b0 + b;
            size_t col = (size_t)t*64 + bg;
            acc0 += xgT[(size_t)(0*HIDD + uu)*MCOL + col];
            acc1 += xgT[(size_t)(1*HIDD + uu)*MCOL + col];
            acc2 += xgT[(size_t)(2*HIDD + uu)*MCOL + col];
            acc3 += xgT[(size_t)(3*HIDD + uu)*MCOL + col];
            float si = sigmf(acc0), sf = sigmf(acc1);
            float tg = tanhf(acc2), so = sigmf(acc3);
            float cn = sf*c + si*tg;
            float hn = so*tanhf(cn);
            if (t < mylen){ c = cn; hprev = hn; }
            hW[((size_t)((t&1)*GRPS + g)*512 + uu)*4 + b] = hprev;
        }
        // group barrier (10 blocks)
        __syncthreads();
        if (tid == 0){
            __hip_atomic_fetch_add(mybar, 1, __ATOMIC_RELEASE, __HIP_MEMORY_SCOPE_AGENT);
            int tgt = UBLK*(t+2);
            while (__hip_atomic_load(mybar, __ATOMIC_RELAXED, __HIP_MEMORY_SCOPE_AGENT) < tgt)
                __builtin_amdgcn_s_sleep(1);
            (void)__hip_atomic_load(mybar, __ATOMIC_ACQUIRE, __HIP_MEMORY_SCOPE_AGENT);
        }
        __syncthreads();
    }
}

// ---------------- q_part: qp[b][n] = sum_k h31[k][b]*g1w[n][k] + g1b[n] ----------------
// hq points at hW buf1: [g][k][b]
__global__ void k_qp(const float* __restrict__ hq, const float* __restrict__ g1w,
                     const float* __restrict__ g1b, float* __restrict__ qp)
{
    int idx = blockIdx.x*blockDim.x + threadIdx.x;
    if (idx >= BATCH*GHID) return;
    int b = idx / GHID, n = idx % GHID;
    const float* wr = g1w + n*548;
    const float* hb = hq + (size_t)(b>>2)*512*4 + (b&3);
    float s = g1b[n];
    for (int k = 0; k < HIDD; ++k) s += hb[k*4]*wr[k];
    qp[idx] = s;
}

// ---------------- i_part/j_part ----------------
__global__ void k_ipjp(const float* __restrict__ conv, const float* __restrict__ g1w,
                       float* __restrict__ ip, float* __restrict__ jp)
{
    int idx = blockIdx.x*blockDim.x + threadIdx.x;
    if (idx >= BATCH*NOBJ*GHID) return;
    int b = idx / (NOBJ*GHID);
    int rem = idx - b*(NOBJ*GHID);
    int o = rem / GHID, n = rem % GHID;
    const float* wj = g1w + n*548 + 500;
    const float* wi = g1w + n*548 + 524;
    float si = 0.f, sj = 0.f;
    #pragma unroll
    for (int c = 0; c < 24; ++c){
        float v = conv[((size_t)b*24 + c)*NOBJ + o];
        sj += v*wj[c];
        si += v*wi[c];
    }
    ip[idx] = si;
    jp[idx] = sj;
}

// ---------------- fused pair kernel: 2 i's x 64 j's per block (acc[2][25], no spill) ----------------
__global__ __launch_bounds__(256, 2) void k_pair(const float* __restrict__ qp, const float* __restrict__ ip,
              const float* __restrict__ jp, const float* __restrict__ g2w,
              const float* __restrict__ g2b, float* __restrict__ part)
{
    __shared__ float jpl[NOBJ][GHID+1];
    __shared__ float basel[2][GHID];
    __shared__ float g2wl[GHID*GHID];
    int b  = blockIdx.x >> 5;
    int ic = blockIdx.x & 31;
    int tid = threadIdx.x;
    for (int i = tid; i < NOBJ*GHID; i += 256){
        int j = i / GHID, k = i % GHID;
        jpl[j][k] = jp[((size_t)b*NOBJ + j)*GHID + k];
    }
    for (int i = tid; i < 2*GHID; i += 256){
        int ii = i / GHID, k = i % GHID;
        basel[ii][k] = qp[b*GHID + k] + ip[((size_t)b*NOBJ + ic*2 + ii)*GHID + k];
    }
    for (int i = tid; i < GHID*GHID; i += 256) g2wl[i] = g2w[i];
    __syncthreads();

    int j  = tid & 63;
    int nt = tid >> 6;
    float acc[2][25] = {};
    for (int k = 0; k < GHID; ++k){
        float jv = jpl[j][k];
        float a0 = fmaxf(basel[0][k] + jv, 0.f);
        float a1 = fmaxf(basel[1][k] + jv, 0.f);
        #pragma unroll
        for (int nn = 0; nn < 25; ++nn){
            float w = g2wl[(nt*25+nn)*GHID + k];
            acc[0][nn] += a0*w;
            acc[1][nn] += a1*w;
        }
    }
    #pragma unroll
    for (int nn = 0; nn < 25; ++nn){
        int n = nt*25 + nn;
        float gb = g2b[n];
        float s = fmaxf(acc[0][nn]+gb, 0.f) + fmaxf(acc[1][nn]+gb, 0.f);
        #pragma unroll
        for (int off = 32; off > 0; off >>= 1) s += __shfl_down(s, off);
        if ((tid & 63) == 0) part[(size_t)blockIdx.x*GHID + n] = s;
    }
}

// ---------------- final: reduce partials, f1, f2, log_softmax ----------------
__global__ __launch_bounds__(256) void k_final(const float* __restrict__ part, const float* __restrict__ f1w,
               const float* __restrict__ f1b, const float* __restrict__ f2w,
               const float* __restrict__ f2b, float* __restrict__ out)
{
    int b = blockIdx.x;
    int tid = threadIdx.x;
    __shared__ float gs[GHID];
    __shared__ float fh[GHID];
    __shared__ float lg[ANSN];
    __shared__ float red[4], red2[4];
    if (tid < GHID){
        float s = 0.f;
        for (int ic = 0; ic < 32; ++ic) s += part[((size_t)b*32 + ic)*GHID + tid];
        gs[tid] = s;
    }
    __syncthreads();
    if (tid < GHID){
        float s = f1b[tid];
        const float* w = f1w + tid*GHID;
        for (int k = 0; k < GHID; ++k) s += gs[k]*w[k];
        fh[tid] = fmaxf(s, 0.f);
    }
    __syncthreads();
    for (int n = tid; n < ANSN; n += 256){
        float s = f2b[n];
        const float* w = f2w + (size_t)n*GHID;
        for (int k = 0; k < GHID; ++k) s += fh[k]*w[k];
        lg[n] = fmaxf(s, 0.f);
    }
    __syncthreads();
    float mx = -1e30f;
    for (int n = tid; n < ANSN; n += 256) mx = fmaxf(mx, lg[n]);
    #pragma unroll
    for (int off = 32; off > 0; off >>= 1) mx = fmaxf(mx, __shfl_xor(mx, off));
    if ((tid & 63) == 0) red[tid >> 6] = mx;
    __syncthreads();
    mx = fmaxf(fmaxf(red[0], red[1]), fmaxf(red[2], red[3]));
    float se = 0.f;
    for (int n = tid; n < ANSN; n += 256) se += expf(lg[n]-mx);
    #pragma unroll
    for (int off = 32; off > 0; off >>= 1) se += __shfl_xor(se, off);
    if ((tid & 63) == 0) red2[tid >> 6] = se;
    __syncthreads();
    se = red2[0]+red2[1]+red2[2]+red2[3];
    float lse = logf(se);
    for (int n = tid; n < ANSN; n += 256) out[(size_t)b*ANSN + n] = lg[n] - mx - lse;
}

extern "C" void kernel_launch(void* const* d_in, const int* in_sizes, int n_in,
                              void* d_out, int out_size, void* d_ws, size_t ws_size,
                              hipStream_t stream)
{
    const int*   sent  = (const int*)  d_in[0];
    const float* conv  = (const float*)d_in[1];
    const int*   lens  = (const int*)  d_in[2];
    const float* table = (const float*)d_in[3];
    const float* W_ih  = (const float*)d_in[4];
    const float* W_hh  = (const float*)d_in[5];
    const float* b_ih  = (const float*)d_in[6];
    const float* b_hh  = (const float*)d_in[7];
    const float* h0    = (const float*)d_in[8];
    const float* c0    = (const float*)d_in[9];
    const float* g1_w  = (const float*)d_in[10];
    const float* g1_b  = (const float*)d_in[11];
    const float* g2_w  = (const float*)d_in[12];
    const float* g2_b  = (const float*)d_in[13];
    const float* f1_w  = (const float*)d_in[14];
    const float* f1_b  = (const float*)d_in[15];
    const float* f2_w  = (const float*)d_in[16];
    const float* f2_b  = (const float*)d_in[17];
    float* out = (float*)d_out;

    float* ws   = (float*)d_ws;
    int*   bar  = (int*)d_ws;                          // 16 groups * 32 ints = 2 KB
    float* hW   = ws + 1024;                           // 2*16*512*4 = 65536
    float* embT = hW + 2*GRPS*512*4;                   // 300*2048
    float* xgT  = embT + (size_t)EMBD*MCOL;            // 2000*2048
    float* qp   = xgT  + (size_t)4*HIDD*MCOL;          // 64*100
    float* ip   = qp   + BATCH*GHID;                   // 64*64*100
    float* jp   = ip   + BATCH*NOBJ*GHID;
    float* part = jp   + BATCH*NOBJ*GHID;              // 2048*100

    // 0. zero barrier counters (every launch -> deterministic across graph replays)
    hipMemsetAsync(bar, 0, GRPS*32*sizeof(int), stream);

    // 1. embedding gather, transposed
    {
        dim3 g(3, SEQL);
        k_embT<<<g, 256, 0, stream>>>(sent, table, embT);
    }

    // 2. xgT = W_ih @ embT + (b_ih+b_hh)
    {
        dim3 g(MCOL/64, (4*HIDD + 63)/64);
        k_gemm_nn<<<g, 256, 0, stream>>>(W_ih, embT, b_ih, b_hh, xgT,
                                         4*HIDD, MCOL, EMBD);
    }

    // 3. LSTM, 160 blocks, group-local barriers (cooperative launch for residency)
    {
        float* hW_p = hW; const float* xgT_p = xgT;
        const float* Whh_p = W_hh; const float* h0_p = h0;
        const float* c0_p = c0; const int* lens_p = lens; int* bar_p = bar;
        void* kargs[] = { (void*)&hW_p, (void*)&xgT_p, (void*)&Whh_p,
                          (void*)&h0_p, (void*)&c0_p, (void*)&lens_p, (void*)&bar_p };
        hipLaunchCooperativeKernel((const void*)k_lstm_v3, dim3(GRPS*UBLK), dim3(256),
                                   kargs, 0, stream);
    }
    const float* hq = hW + (size_t)GRPS*512*4;   // buf1 holds h(31)

    // 4. g_mlp layer-1 partials
    k_qp<<<(BATCH*GHID + 255)/256, 256, 0, stream>>>(hq, g1_w, g1_b, qp);
    k_ipjp<<<(BATCH*NOBJ*GHID + 255)/256, 256, 0, stream>>>(conv, g1_w, ip, jp);

    // 5. fused pair kernel (2 i's per block) -> partial sums
    k_pair<<<BATCH*32, 256, 0, stream>>>(qp, ip, jp, g2_w, g2_b, part);

    // 6. final MLP + log_softmax
    k_final<<<BATCH, 256, 0, stream>>>(part, f1_w, f1_b, f2_w, f2_b, out);
}

// Round 4
// 1164.636 us; speedup vs baseline: 2.2786x; 2.2786x over previous
//
#include <hip/hip_runtime.h>
#include <cmath>

#define BATCH 64
#define SEQL  32
#define EMBD  300
#define HIDD  500
#define NOBJ  64
#define GHID  100
#define ANSN  1000
#define MCOL  2048   // t*64+b column dimension
#define LBLK  250    // LSTM blocks (2 units each)

__device__ __forceinline__ float sigmf(float x){ return 1.f/(1.f+expf(-x)); }

// ---------------- embT[k][t*64+b] = table[sent[b*32+t]][k] ----------------
__global__ void k_embT(const int* __restrict__ sent, const float* __restrict__ table,
                       float* __restrict__ embT)
{
    __shared__ float T[64][101];
    int t  = blockIdx.y;
    int k0 = blockIdx.x * 100;
    int tid = threadIdx.x;
    for (int i = tid; i < 64*100; i += 256){
        int b = i / 100, k = i - b*100;
        T[b][k] = table[(size_t)sent[b*SEQL + t]*EMBD + k0 + k];
    }
    __syncthreads();
    for (int i = tid; i < 100*64; i += 256){
        int k = i >> 6, b = i & 63;
        embT[(size_t)(k0+k)*MCOL + t*64 + b] = T[b][k];
    }
}

// ---------------- NN GEMM: C[n][m] = sum_k A[n][k]*B[k][m] + bias0[n]+bias1[n] ----------------
__global__ __launch_bounds__(256) void k_gemm_nn(const float* __restrict__ A, const float* __restrict__ B,
                 const float* __restrict__ bias0, const float* __restrict__ bias1,
                 float* __restrict__ C, int N, int M, int K)
{
    __shared__ float As[16][65];
    __shared__ float Bs[16][65];
    int n0 = blockIdx.y*64, m0 = blockIdx.x*64;
    int tid = threadIdx.x, tx = tid & 15, ty = tid >> 4;
    float acc[4][4] = {};
    for (int k0 = 0; k0 < K; k0 += 16){
        for (int i = tid; i < 64*16; i += 256){
            int n = i >> 4, k = i & 15;
            As[k][n] = (n0+n < N && k0+k < K) ? A[(size_t)(n0+n)*K + k0+k] : 0.f;
        }
        for (int i = tid; i < 16*64; i += 256){
            int k = i >> 6, m = i & 63;
            Bs[k][m] = (k0+k < K) ? B[(size_t)(k0+k)*M + m0+m] : 0.f;
        }
        __syncthreads();
        #pragma unroll
        for (int kk = 0; kk < 16; ++kk){
            float a[4], b[4];
            #pragma unroll
            for (int i=0;i<4;i++) a[i] = As[kk][ty*4+i];
            #pragma unroll
            for (int j=0;j<4;j++) b[j] = Bs[kk][tx*4+j];
            #pragma unroll
            for (int i=0;i<4;i++)
                #pragma unroll
                for (int j=0;j<4;j++) acc[i][j] += a[i]*b[j];
        }
        __syncthreads();
    }
    #pragma unroll
    for (int i=0;i<4;i++){
        int n = n0 + ty*4 + i;
        if (n >= N) continue;
        float bsum = bias0[n] + bias1[n];
        float4 v;
        v.x = acc[i][0]+bsum; v.y = acc[i][1]+bsum; v.z = acc[i][2]+bsum; v.w = acc[i][3]+bsum;
        *(float4*)(C + (size_t)n*M + m0 + tx*4) = v;
    }
}

// ---------------- flat device barrier: monotonic counter, all LBLK blocks ----------------
__device__ __forceinline__ void gbar(int* bar, int target)
{
    __syncthreads();
    if (threadIdx.x == 0){
        __hip_atomic_fetch_add(bar, 1, __ATOMIC_RELEASE, __HIP_MEMORY_SCOPE_AGENT);
        while (__hip_atomic_load(bar, __ATOMIC_RELAXED, __HIP_MEMORY_SCOPE_AGENT) < target)
            __builtin_amdgcn_s_sleep(4);
        (void)__hip_atomic_load(bar, __ATOMIC_ACQUIRE, __HIP_MEMORY_SCOPE_AGENT);
    }
    __syncthreads();
}

// ---------------- LSTM v4: 250 blocks x 2 units; scalar W loads; double-buffered h ----------------
// hW layout: [buf][k 0..511][b 0..63]; step t reads buf (t&1)^1, writes buf t&1; h(-1) in buf1.
// wave w stages k-quarter [128w,128w+128) of h into its private LDS region, computes the
// 8 gate-rows over that quarter with wave-uniform (s_load) W_hh float4s, then cross-wave reduce.
__global__ __launch_bounds__(256, 1) void k_lstm_v4(float* __restrict__ hW,
    const float* __restrict__ xgT, const float* __restrict__ Whh,
    const float* __restrict__ h0, const float* __restrict__ c0,
    const int* __restrict__ lens, int* __restrict__ bar)
{
    __shared__ float hs[4][8192];   // 128 KB: [wave][k_local*64 + b]
    __shared__ float gl[2048];      // 8 KB: [wave*8 + r][b] partial gates

    int tid  = threadIdx.x;
    int bid  = blockIdx.x;
    int u0   = bid * 2;
    int w    = __builtin_amdgcn_readfirstlane(tid >> 6);
    int lane = tid & 63;

    // persistent pointwise state (threads 0..127): uu = tid>>6, b = lane
    float cprev = 0.f, hprev = 0.f; int mylen = 0;
    if (tid < 128){
        int b = lane, uu = tid >> 6;
        cprev = c0[b*HIDD + u0 + uu];
        hprev = h0[b*HIDD + u0 + uu];
        mylen = lens[b];
        hW[(size_t)(1*512 + u0 + uu)*64 + b] = hprev;       // h(-1) -> buf1
    }
    if (bid == 0){                   // zero pad rows 500..511, both buffers
        for (int i = tid; i < 2*12*64; i += 256){
            int buf = i / 768, rem = i - buf*768;
            hW[(size_t)(buf*512 + 500 + (rem >> 6))*64 + (rem & 63)] = 0.f;
        }
    }
    gbar(bar, LBLK);                 // init barrier (phase 0)

    const int kq0 = w * 128;

    for (int t = 0; t < SEQL; ++t){
        // stage this wave's k-quarter of h(t-1) into hs[w] (wave-private region)
        {
            const float4* src = (const float4*)(hW + (size_t)((((t&1)^1)*512) + kq0)*64);
            float4* dst = (float4*)(&hs[w][0]);
            #pragma unroll
            for (int i = 0; i < 32; ++i)
                dst[i*64 + lane] = src[i*64 + lane];
        }
        float acc[8] = {0,0,0,0,0,0,0,0};
        #pragma unroll 4
        for (int k4 = 0; k4 < 128; k4 += 4){
            int kk = kq0 + k4;
            if (kk < HIDD){                      // wave-uniform tail guard
                float a0 = hs[w][(k4+0)*64 + lane];
                float a1 = hs[w][(k4+1)*64 + lane];
                float a2 = hs[w][(k4+2)*64 + lane];
                float a3 = hs[w][(k4+3)*64 + lane];
                #pragma unroll
                for (int r = 0; r < 8; ++r){
                    int row = (r>>1)*HIDD + u0 + (r&1);   // gate g=r>>1, unit uu=r&1
                    float4 wv = *(const float4*)(Whh + (size_t)row*HIDD + kk);  // uniform -> s_load
                    acc[r] += a0*wv.x + a1*wv.y + a2*wv.z + a3*wv.w;
                }
            }
        }
        #pragma unroll
        for (int r = 0; r < 8; ++r) gl[(w*8 + r)*64 + lane] = acc[r];
        __syncthreads();
        if (tid < 128){
            int b = lane, uu = tid >> 6;
            float g4[4];
            #pragma unroll
            for (int g = 0; g < 4; ++g){
                int r = g*2 + uu;
                float s = gl[r*64+b] + gl[(8+r)*64+b] + gl[(16+r)*64+b] + gl[(24+r)*64+b];
                s += xgT[(size_t)(g*HIDD + u0 + uu)*MCOL + t*64 + b];
                g4[g] = s;
            }
            float si = sigmf(g4[0]);
            float sf = sigmf(g4[1]);
            float tg = tanhf(g4[2]);
            float so = sigmf(g4[3]);
            float cn = sf*cprev + si*tg;
            float hn = so*tanhf(cn);
            if (t < mylen){ cprev = cn; hprev = hn; }
            hW[(size_t)((t&1)*512 + u0 + uu)*64 + b] = hprev;
        }
        gbar(bar, LBLK*(t+2));
    }
}

// ---------------- q_part: qp[b][n] = sum_k h31[k][b]*g1w[n][k] + g1b[n] ----------------
// hq = hW buf1 base: [k][b]
__global__ void k_qp(const float* __restrict__ hq, const float* __restrict__ g1w,
                     const float* __restrict__ g1b, float* __restrict__ qp)
{
    int idx = blockIdx.x*blockDim.x + threadIdx.x;
    if (idx >= BATCH*GHID) return;
    int b = idx / GHID, n = idx % GHID;
    const float* wr = g1w + n*548;
    float s = g1b[n];
    for (int k = 0; k < HIDD; ++k) s += hq[k*64 + b]*wr[k];
    qp[idx] = s;
}

// ---------------- i_part/j_part ----------------
__global__ void k_ipjp(const float* __restrict__ conv, const float* __restrict__ g1w,
                       float* __restrict__ ip, float* __restrict__ jp)
{
    int idx = blockIdx.x*blockDim.x + threadIdx.x;
    if (idx >= BATCH*NOBJ*GHID) return;
    int b = idx / (NOBJ*GHID);
    int rem = idx - b*(NOBJ*GHID);
    int o = rem / GHID, n = rem % GHID;
    const float* wj = g1w + n*548 + 500;
    const float* wi = g1w + n*548 + 524;
    float si = 0.f, sj = 0.f;
    #pragma unroll
    for (int c = 0; c < 24; ++c){
        float v = conv[((size_t)b*24 + c)*NOBJ + o];
        sj += v*wj[c];
        si += v*wi[c];
    }
    ip[idx] = si;
    jp[idx] = sj;
}

// ---------------- fused pair kernel: 2 i's x 64 j's per block ----------------
__global__ __launch_bounds__(256, 2) void k_pair(const float* __restrict__ qp, const float* __restrict__ ip,
              const float* __restrict__ jp, const float* __restrict__ g2w,
              const float* __restrict__ g2b, float* __restrict__ part)
{
    __shared__ float jpl[NOBJ][GHID+1];
    __shared__ float basel[2][GHID];
    __shared__ float g2wl[GHID*GHID];
    int b  = blockIdx.x >> 5;
    int ic = blockIdx.x & 31;
    int tid = threadIdx.x;
    for (int i = tid; i < NOBJ*GHID; i += 256){
        int j = i / GHID, k = i % GHID;
        jpl[j][k] = jp[((size_t)b*NOBJ + j)*GHID + k];
    }
    for (int i = tid; i < 2*GHID; i += 256){
        int ii = i / GHID, k = i % GHID;
        basel[ii][k] = qp[b*GHID + k] + ip[((size_t)b*NOBJ + ic*2 + ii)*GHID + k];
    }
    for (int i = tid; i < GHID*GHID; i += 256) g2wl[i] = g2w[i];
    __syncthreads();

    int j  = tid & 63;
    int nt = tid >> 6;
    float acc[2][25] = {};
    for (int k = 0; k < GHID; ++k){
        float jv = jpl[j][k];
        float a0 = fmaxf(basel[0][k] + jv, 0.f);
        float a1 = fmaxf(basel[1][k] + jv, 0.f);
        #pragma unroll
        for (int nn = 0; nn < 25; ++nn){
            float w = g2wl[(nt*25+nn)*GHID + k];
            acc[0][nn] += a0*w;
            acc[1][nn] += a1*w;
        }
    }
    #pragma unroll
    for (int nn = 0; nn < 25; ++nn){
        int n = nt*25 + nn;
        float gb = g2b[n];
        float s = fmaxf(acc[0][nn]+gb, 0.f) + fmaxf(acc[1][nn]+gb, 0.f);
        #pragma unroll
        for (int off = 32; off > 0; off >>= 1) s += __shfl_down(s, off);
        if ((tid & 63) == 0) part[(size_t)blockIdx.x*GHID + n] = s;
    }
}

// ---------------- final: reduce partials, f1, f2, log_softmax ----------------
__global__ __launch_bounds__(256) void k_final(const float* __restrict__ part, const float* __restrict__ f1w,
               const float* __restrict__ f1b, const float* __restrict__ f2w,
               const float* __restrict__ f2b, float* __restrict__ out)
{
    int b = blockIdx.x;
    int tid = threadIdx.x;
    __shared__ float gs[GHID];
    __shared__ float fh[GHID];
    __shared__ float lg[ANSN];
    __shared__ float red[4], red2[4];
    if (tid < GHID){
        float s = 0.f;
        for (int ic = 0; ic < 32; ++ic) s += part[((size_t)b*32 + ic)*GHID + tid];
        gs[tid] = s;
    }
    __syncthreads();
    if (tid < GHID){
        float s = f1b[tid];
        const float* w = f1w + tid*GHID;
        for (int k = 0; k < GHID; ++k) s += gs[k]*w[k];
        fh[tid] = fmaxf(s, 0.f);
    }
    __syncthreads();
    for (int n = tid; n < ANSN; n += 256){
        float s = f2b[n];
        const float* w = f2w + (size_t)n*GHID;
        for (int k = 0; k < GHID; ++k) s += fh[k]*w[k];
        lg[n] = fmaxf(s, 0.f);
    }
    __syncthreads();
    float mx = -1e30f;
    for (int n = tid; n < ANSN; n += 256) mx = fmaxf(mx, lg[n]);
    #pragma unroll
    for (int off = 32; off > 0; off >>= 1) mx = fmaxf(mx, __shfl_xor(mx, off));
    if ((tid & 63) == 0) red[tid >> 6] = mx;
    __syncthreads();
    mx = fmaxf(fmaxf(red[0], red[1]), fmaxf(red[2], red[3]));
    float se = 0.f;
    for (int n = tid; n < ANSN; n += 256) se += expf(lg[n]-mx);
    #pragma unroll
    for (int off = 32; off > 0; off >>= 1) se += __shfl_xor(se, off);
    if ((tid & 63) == 0) red2[tid >> 6] = se;
    __syncthreads();
    se = red2[0]+red2[1]+red2[2]+red2[3];
    float lse = logf(se);
    for (int n = tid; n < ANSN; n += 256) out[(size_t)b*ANSN + n] = lg[n] - mx - lse;
}

extern "C" void kernel_launch(void* const* d_in, const int* in_sizes, int n_in,
                              void* d_out, int out_size, void* d_ws, size_t ws_size,
                              hipStream_t stream)
{
    const int*   sent  = (const int*)  d_in[0];
    const float* conv  = (const float*)d_in[1];
    const int*   lens  = (const int*)  d_in[2];
    const float* table = (const float*)d_in[3];
    const float* W_ih  = (const float*)d_in[4];
    const float* W_hh  = (const float*)d_in[5];
    const float* b_ih  = (const float*)d_in[6];
    const float* b_hh  = (const float*)d_in[7];
    const float* h0    = (const float*)d_in[8];
    const float* c0    = (const float*)d_in[9];
    const float* g1_w  = (const float*)d_in[10];
    const float* g1_b  = (const float*)d_in[11];
    const float* g2_w  = (const float*)d_in[12];
    const float* g2_b  = (const float*)d_in[13];
    const float* f1_w  = (const float*)d_in[14];
    const float* f1_b  = (const float*)d_in[15];
    const float* f2_w  = (const float*)d_in[16];
    const float* f2_b  = (const float*)d_in[17];
    float* out = (float*)d_out;

    float* ws   = (float*)d_ws;
    int*   bar  = (int*)d_ws;                          // 1 counter (1024 floats reserved)
    float* hW   = ws + 1024;                           // 2*512*64 = 65536
    float* embT = hW + 2*512*64;                       // 300*2048
    float* xgT  = embT + (size_t)EMBD*MCOL;            // 2000*2048
    float* qp   = xgT  + (size_t)4*HIDD*MCOL;          // 64*100
    float* ip   = qp   + BATCH*GHID;                   // 64*64*100
    float* jp   = ip   + BATCH*NOBJ*GHID;
    float* part = jp   + BATCH*NOBJ*GHID;              // 2048*100

    // 0. zero barrier counter (every launch -> deterministic across graph replays)
    hipMemsetAsync(bar, 0, 256, stream);

    // 1. embedding gather, transposed
    {
        dim3 g(3, SEQL);
        k_embT<<<g, 256, 0, stream>>>(sent, table, embT);
    }

    // 2. xgT = W_ih @ embT + (b_ih+b_hh)
    {
        dim3 g(MCOL/64, (4*HIDD + 63)/64);
        k_gemm_nn<<<g, 256, 0, stream>>>(W_ih, embT, b_ih, b_hh, xgT,
                                         4*HIDD, MCOL, EMBD);
    }

    // 3. LSTM, 250 blocks, custom flat device barrier (cooperative launch for residency)
    {
        float* hW_p = hW; const float* xgT_p = xgT;
        const float* Whh_p = W_hh; const float* h0_p = h0;
        const float* c0_p = c0; const int* lens_p = lens; int* bar_p = bar;
        void* kargs[] = { (void*)&hW_p, (void*)&xgT_p, (void*)&Whh_p,
                          (void*)&h0_p, (void*)&c0_p, (void*)&lens_p, (void*)&bar_p };
        hipLaunchCooperativeKernel((const void*)k_lstm_v4, dim3(LBLK), dim3(256),
                                   kargs, 0, stream);
    }
    const float* hq = hW + (size_t)512*64;   // buf1 holds h(31)

    // 4. g_mlp layer-1 partials
    k_qp<<<(BATCH*GHID + 255)/256, 256, 0, stream>>>(hq, g1_w, g1_b, qp);
    k_ipjp<<<(BATCH*NOBJ*GHID + 255)/256, 256, 0, stream>>>(conv, g1_w, ip, jp);

    // 5. fused pair kernel (2 i's per block) -> partial sums
    k_pair<<<BATCH*32, 256, 0, stream>>>(qp, ip, jp, g2_w, g2_b, part);

    // 6. final MLP + log_softmax
    k_final<<<BATCH, 256, 0, stream>>>(part, f1_w, f1_b, f2_w, f2_b, out);
}

// Round 5
// 916.272 us; speedup vs baseline: 2.8963x; 1.2711x over previous
//
#include <hip/hip_runtime.h>
#include <cmath>

#define BATCH 64
#define SEQL  32
#define EMBD  300
#define HIDD  500
#define NOBJ  64
#define GHID  100
#define ANSN  1000
#define MCOL  2048   // t*64+b column dimension
#define LBLK  250    // LSTM blocks (2 units each)
#define SLOTP 32     // slot padding in ints (128 B)

__device__ __forceinline__ float sigmf(float x){ return 1.f/(1.f+expf(-x)); }

// ---------------- embT[k][t*64+b] = table[sent[b*32+t]][k] ----------------
__global__ void k_embT(const int* __restrict__ sent, const float* __restrict__ table,
                       float* __restrict__ embT)
{
    __shared__ float T[64][101];
    int t  = blockIdx.y;
    int k0 = blockIdx.x * 100;
    int tid = threadIdx.x;
    for (int i = tid; i < 64*100; i += 256){
        int b = i / 100, k = i - b*100;
        T[b][k] = table[(size_t)sent[b*SEQL + t]*EMBD + k0 + k];
    }
    __syncthreads();
    for (int i = tid; i < 100*64; i += 256){
        int k = i >> 6, b = i & 63;
        embT[(size_t)(k0+k)*MCOL + t*64 + b] = T[b][k];
    }
}

// ---------------- NN GEMM: C[n][m] = sum_k A[n][k]*B[k][m] + bias0[n]+bias1[n] ----------------
__global__ __launch_bounds__(256) void k_gemm_nn(const float* __restrict__ A, const float* __restrict__ B,
                 const float* __restrict__ bias0, const float* __restrict__ bias1,
                 float* __restrict__ C, int N, int M, int K)
{
    __shared__ float As[16][65];
    __shared__ float Bs[16][65];
    int n0 = blockIdx.y*64, m0 = blockIdx.x*64;
    int tid = threadIdx.x, tx = tid & 15, ty = tid >> 4;
    float acc[4][4] = {};
    for (int k0 = 0; k0 < K; k0 += 16){
        for (int i = tid; i < 64*16; i += 256){
            int n = i >> 4, k = i & 15;
            As[k][n] = (n0+n < N && k0+k < K) ? A[(size_t)(n0+n)*K + k0+k] : 0.f;
        }
        for (int i = tid; i < 16*64; i += 256){
            int k = i >> 6, m = i & 63;
            Bs[k][m] = (k0+k < K) ? B[(size_t)(k0+k)*M + m0+m] : 0.f;
        }
        __syncthreads();
        #pragma unroll
        for (int kk = 0; kk < 16; ++kk){
            float a[4], b[4];
            #pragma unroll
            for (int i=0;i<4;i++) a[i] = As[kk][ty*4+i];
            #pragma unroll
            for (int j=0;j<4;j++) b[j] = Bs[kk][tx*4+j];
            #pragma unroll
            for (int i=0;i<4;i++)
                #pragma unroll
                for (int j=0;j<4;j++) acc[i][j] += a[i]*b[j];
        }
        __syncthreads();
    }
    #pragma unroll
    for (int i=0;i<4;i++){
        int n = n0 + ty*4 + i;
        if (n >= N) continue;
        float bsum = bias0[n] + bias1[n];
        float4 v;
        v.x = acc[i][0]+bsum; v.y = acc[i][1]+bsum; v.z = acc[i][2]+bsum; v.w = acc[i][3]+bsum;
        *(float4*)(C + (size_t)n*M + m0 + tx*4) = v;
    }
}

// ---------------- distributed barrier: per-block slots + block-0 aggregator ----------------
// slots[i] (128B apart) for blocks 1..LBLK-1; go = broadcast word. seq is monotonic.
__device__ __forceinline__ void gbar2(int* slots, int* go, int seq)
{
    __syncthreads();
    if (blockIdx.x == 0){
        if (threadIdx.x < LBLK-1){
            int* s = slots + threadIdx.x*SLOTP;
            while (__hip_atomic_load(s, __ATOMIC_RELAXED, __HIP_MEMORY_SCOPE_AGENT) < seq)
                __builtin_amdgcn_s_sleep(1);
            (void)__hip_atomic_load(s, __ATOMIC_ACQUIRE, __HIP_MEMORY_SCOPE_AGENT);
        }
        __syncthreads();
        if (threadIdx.x == 0)
            __hip_atomic_store(go, seq, __ATOMIC_RELEASE, __HIP_MEMORY_SCOPE_AGENT);
        __syncthreads();
    } else {
        if (threadIdx.x == 0){
            __hip_atomic_store(slots + (blockIdx.x-1)*SLOTP, seq,
                               __ATOMIC_RELEASE, __HIP_MEMORY_SCOPE_AGENT);
            while (__hip_atomic_load(go, __ATOMIC_RELAXED, __HIP_MEMORY_SCOPE_AGENT) < seq)
                __builtin_amdgcn_s_sleep(1);
            (void)__hip_atomic_load(go, __ATOMIC_ACQUIRE, __HIP_MEMORY_SCOPE_AGENT);
        }
        __syncthreads();
    }
}

// ---------------- LSTM v5: v4 compute + distributed barrier ----------------
// hW layout: [buf][k 0..511][b 0..63]; step t reads buf (t&1)^1, writes buf t&1; h(-1) in buf1.
__global__ __launch_bounds__(256, 1) void k_lstm_v5(float* __restrict__ hW,
    const float* __restrict__ xgT, const float* __restrict__ Whh,
    const float* __restrict__ h0, const float* __restrict__ c0,
    const int* __restrict__ lens, int* __restrict__ slots, int* __restrict__ go)
{
    __shared__ float hs[4][8192];   // 128 KB: [wave][k_local*64 + b]
    __shared__ float gl[2048];      // 8 KB: [wave*8 + r][b] partial gates

    int tid  = threadIdx.x;
    int bid  = blockIdx.x;
    int u0   = bid * 2;
    int w    = __builtin_amdgcn_readfirstlane(tid >> 6);
    int lane = tid & 63;

    // persistent pointwise state (threads 0..127): uu = tid>>6, b = lane
    float cprev = 0.f, hprev = 0.f; int mylen = 0;
    if (tid < 128){
        int b = lane, uu = tid >> 6;
        cprev = c0[b*HIDD + u0 + uu];
        hprev = h0[b*HIDD + u0 + uu];
        mylen = lens[b];
        hW[(size_t)(1*512 + u0 + uu)*64 + b] = hprev;       // h(-1) -> buf1
    }
    if (bid == 0){                   // zero pad rows 500..511, both buffers
        for (int i = tid; i < 2*12*64; i += 256){
            int buf = i / 768, rem = i - buf*768;
            hW[(size_t)(buf*512 + 500 + (rem >> 6))*64 + (rem & 63)] = 0.f;
        }
    }
    gbar2(slots, go, 1);             // init barrier

    const int kq0 = w * 128;

    for (int t = 0; t < SEQL; ++t){
        // stage this wave's k-quarter of h(t-1) into hs[w] (wave-private region)
        {
            const float4* src = (const float4*)(hW + (size_t)((((t&1)^1)*512) + kq0)*64);
            float4* dst = (float4*)(&hs[w][0]);
            #pragma unroll
            for (int i = 0; i < 32; ++i)
                dst[i*64 + lane] = src[i*64 + lane];
        }
        float acc[8] = {0,0,0,0,0,0,0,0};
        #pragma unroll 4
        for (int k4 = 0; k4 < 128; k4 += 4){
            int kk = kq0 + k4;
            if (kk < HIDD){                      // wave-uniform tail guard
                float a0 = hs[w][(k4+0)*64 + lane];
                float a1 = hs[w][(k4+1)*64 + lane];
                float a2 = hs[w][(k4+2)*64 + lane];
                float a3 = hs[w][(k4+3)*64 + lane];
                #pragma unroll
                for (int r = 0; r < 8; ++r){
                    int row = (r>>1)*HIDD + u0 + (r&1);   // gate g=r>>1, unit uu=r&1
                    float4 wv = *(const float4*)(Whh + (size_t)row*HIDD + kk);  // uniform -> s_load
                    acc[r] += a0*wv.x + a1*wv.y + a2*wv.z + a3*wv.w;
                }
            }
        }
        #pragma unroll
        for (int r = 0; r < 8; ++r) gl[(w*8 + r)*64 + lane] = acc[r];
        __syncthreads();
        if (tid < 128){
            int b = lane, uu = tid >> 6;
            float g4[4];
            #pragma unroll
            for (int g = 0; g < 4; ++g){
                int r = g*2 + uu;
                float s = gl[r*64+b] + gl[(8+r)*64+b] + gl[(16+r)*64+b] + gl[(24+r)*64+b];
                s += xgT[(size_t)(g*HIDD + u0 + uu)*MCOL + t*64 + b];
                g4[g] = s;
            }
            float si = sigmf(g4[0]);
            float sf = sigmf(g4[1]);
            float tg = tanhf(g4[2]);
            float so = sigmf(g4[3]);
            float cn = sf*cprev + si*tg;
            float hn = so*tanhf(cn);
            if (t < mylen){ cprev = cn; hprev = hn; }
            hW[(size_t)((t&1)*512 + u0 + uu)*64 + b] = hprev;
        }
        gbar2(slots, go, t + 2);
    }
}

// ---------------- q_part: qp[b][n] = sum_k h31[k][b]*g1w[n][k] + g1b[n] ----------------
__global__ void k_qp(const float* __restrict__ hq, const float* __restrict__ g1w,
                     const float* __restrict__ g1b, float* __restrict__ qp)
{
    int idx = blockIdx.x*blockDim.x + threadIdx.x;
    if (idx >= BATCH*GHID) return;
    int b = idx / GHID, n = idx % GHID;
    const float* wr = g1w + n*548;
    float s = g1b[n];
    for (int k = 0; k < HIDD; ++k) s += hq[k*64 + b]*wr[k];
    qp[idx] = s;
}

// ---------------- i_part/j_part ----------------
__global__ void k_ipjp(const float* __restrict__ conv, const float* __restrict__ g1w,
                       float* __restrict__ ip, float* __restrict__ jp)
{
    int idx = blockIdx.x*blockDim.x + threadIdx.x;
    if (idx >= BATCH*NOBJ*GHID) return;
    int b = idx / (NOBJ*GHID);
    int rem = idx - b*(NOBJ*GHID);
    int o = rem / GHID, n = rem % GHID;
    const float* wj = g1w + n*548 + 500;
    const float* wi = g1w + n*548 + 524;
    float si = 0.f, sj = 0.f;
    #pragma unroll
    for (int c = 0; c < 24; ++c){
        float v = conv[((size_t)b*24 + c)*NOBJ + o];
        sj += v*wj[c];
        si += v*wi[c];
    }
    ip[idx] = si;
    jp[idx] = sj;
}

// ---------------- fused pair kernel: 2 i's x 64 j's per block ----------------
__global__ __launch_bounds__(256, 2) void k_pair(const float* __restrict__ qp, const float* __restrict__ ip,
              const float* __restrict__ jp, const float* __restrict__ g2w,
              const float* __restrict__ g2b, float* __restrict__ part)
{
    __shared__ float jpl[NOBJ][GHID+1];
    __shared__ float basel[2][GHID];
    __shared__ float g2wl[GHID*GHID];
    int b  = blockIdx.x >> 5;
    int ic = blockIdx.x & 31;
    int tid = threadIdx.x;
    for (int i = tid; i < NOBJ*GHID; i += 256){
        int j = i / GHID, k = i % GHID;
        jpl[j][k] = jp[((size_t)b*NOBJ + j)*GHID + k];
    }
    for (int i = tid; i < 2*GHID; i += 256){
        int ii = i / GHID, k = i % GHID;
        basel[ii][k] = qp[b*GHID + k] + ip[((size_t)b*NOBJ + ic*2 + ii)*GHID + k];
    }
    for (int i = tid; i < GHID*GHID; i += 256) g2wl[i] = g2w[i];
    __syncthreads();

    int j  = tid & 63;
    int nt = tid >> 6;
    float acc[2][25] = {};
    for (int k = 0; k < GHID; ++k){
        float jv = jpl[j][k];
        float a0 = fmaxf(basel[0][k] + jv, 0.f);
        float a1 = fmaxf(basel[1][k] + jv, 0.f);
        #pragma unroll
        for (int nn = 0; nn < 25; ++nn){
            float w = g2wl[(nt*25+nn)*GHID + k];
            acc[0][nn] += a0*w;
            acc[1][nn] += a1*w;
        }
    }
    #pragma unroll
    for (int nn = 0; nn < 25; ++nn){
        int n = nt*25 + nn;
        float gb = g2b[n];
        float s = fmaxf(acc[0][nn]+gb, 0.f) + fmaxf(acc[1][nn]+gb, 0.f);
        #pragma unroll
        for (int off = 32; off > 0; off >>= 1) s += __shfl_down(s, off);
        if ((tid & 63) == 0) part[(size_t)blockIdx.x*GHID + n] = s;
    }
}

// ---------------- final: reduce partials, f1, f2, log_softmax ----------------
__global__ __launch_bounds__(256) void k_final(const float* __restrict__ part, const float* __restrict__ f1w,
               const float* __restrict__ f1b, const float* __restrict__ f2w,
               const float* __restrict__ f2b, float* __restrict__ out)
{
    int b = blockIdx.x;
    int tid = threadIdx.x;
    __shared__ float gs[GHID];
    __shared__ float fh[GHID];
    __shared__ float lg[ANSN];
    __shared__ float red[4], red2[4];
    if (tid < GHID){
        float s = 0.f;
        for (int ic = 0; ic < 32; ++ic) s += part[((size_t)b*32 + ic)*GHID + tid];
        gs[tid] = s;
    }
    __syncthreads();
    if (tid < GHID){
        float s = f1b[tid];
        const float* w = f1w + tid*GHID;
        for (int k = 0; k < GHID; ++k) s += gs[k]*w[k];
        fh[tid] = fmaxf(s, 0.f);
    }
    __syncthreads();
    for (int n = tid; n < ANSN; n += 256){
        float s = f2b[n];
        const float* w = f2w + (size_t)n*GHID;
        for (int k = 0; k < GHID; ++k) s += fh[k]*w[k];
        lg[n] = fmaxf(s, 0.f);
    }
    __syncthreads();
    float mx = -1e30f;
    for (int n = tid; n < ANSN; n += 256) mx = fmaxf(mx, lg[n]);
    #pragma unroll
    for (int off = 32; off > 0; off >>= 1) mx = fmaxf(mx, __shfl_xor(mx, off));
    if ((tid & 63) == 0) red[tid >> 6] = mx;
    __syncthreads();
    mx = fmaxf(fmaxf(red[0], red[1]), fmaxf(red[2], red[3]));
    float se = 0.f;
    for (int n = tid; n < ANSN; n += 256) se += expf(lg[n]-mx);
    #pragma unroll
    for (int off = 32; off > 0; off >>= 1) se += __shfl_xor(se, off);
    if ((tid & 63) == 0) red2[tid >> 6] = se;
    __syncthreads();
    se = red2[0]+red2[1]+red2[2]+red2[3];
    float lse = logf(se);
    for (int n = tid; n < ANSN; n += 256) out[(size_t)b*ANSN + n] = lg[n] - mx - lse;
}

extern "C" void kernel_launch(void* const* d_in, const int* in_sizes, int n_in,
                              void* d_out, int out_size, void* d_ws, size_t ws_size,
                              hipStream_t stream)
{
    const int*   sent  = (const int*)  d_in[0];
    const float* conv  = (const float*)d_in[1];
    const int*   lens  = (const int*)  d_in[2];
    const float* table = (const float*)d_in[3];
    const float* W_ih  = (const float*)d_in[4];
    const float* W_hh  = (const float*)d_in[5];
    const float* b_ih  = (const float*)d_in[6];
    const float* b_hh  = (const float*)d_in[7];
    const float* h0    = (const float*)d_in[8];
    const float* c0    = (const float*)d_in[9];
    const float* g1_w  = (const float*)d_in[10];
    const float* g1_b  = (const float*)d_in[11];
    const float* g2_w  = (const float*)d_in[12];
    const float* g2_b  = (const float*)d_in[13];
    const float* f1_w  = (const float*)d_in[14];
    const float* f1_b  = (const float*)d_in[15];
    const float* f2_w  = (const float*)d_in[16];
    const float* f2_b  = (const float*)d_in[17];
    float* out = (float*)d_out;

    float* ws   = (float*)d_ws;
    int*   go   = (int*)d_ws;                          // 1 word (own line)
    int*   slots= (int*)d_ws + SLOTP;                  // 249 slots * 32 ints
    float* hW   = ws + 16384;                          // 2*512*64 = 65536  (64 KB barrier region)
    float* embT = hW + 2*512*64;                       // 300*2048
    float* xgT  = embT + (size_t)EMBD*MCOL;            // 2000*2048
    float* qp   = xgT  + (size_t)4*HIDD*MCOL;          // 64*100
    float* ip   = qp   + BATCH*GHID;                   // 64*64*100
    float* jp   = ip   + BATCH*NOBJ*GHID;
    float* part = jp   + BATCH*NOBJ*GHID;              // 2048*100

    // 0. zero barrier region (every launch -> deterministic across graph replays)
    hipMemsetAsync(go, 0, 16384*sizeof(float), stream);

    // 1. embedding gather, transposed
    {
        dim3 g(3, SEQL);
        k_embT<<<g, 256, 0, stream>>>(sent, table, embT);
    }

    // 2. xgT = W_ih @ embT + (b_ih+b_hh)
    {
        dim3 g(MCOL/64, (4*HIDD + 63)/64);
        k_gemm_nn<<<g, 256, 0, stream>>>(W_ih, embT, b_ih, b_hh, xgT,
                                         4*HIDD, MCOL, EMBD);
    }

    // 3. LSTM, 250 blocks, distributed barrier (cooperative launch for residency)
    {
        float* hW_p = hW; const float* xgT_p = xgT;
        const float* Whh_p = W_hh; const float* h0_p = h0;
        const float* c0_p = c0; const int* lens_p = lens;
        int* slots_p = slots; int* go_p = go;
        void* kargs[] = { (void*)&hW_p, (void*)&xgT_p, (void*)&Whh_p,
                          (void*)&h0_p, (void*)&c0_p, (void*)&lens_p,
                          (void*)&slots_p, (void*)&go_p };
        hipLaunchCooperativeKernel((const void*)k_lstm_v5, dim3(LBLK), dim3(256),
                                   kargs, 0, stream);
    }
    const float* hq = hW + (size_t)512*64;   // buf1 holds h(31)

    // 4. g_mlp layer-1 partials
    k_qp<<<(BATCH*GHID + 255)/256, 256, 0, stream>>>(hq, g1_w, g1_b, qp);
    k_ipjp<<<(BATCH*NOBJ*GHID + 255)/256, 256, 0, stream>>>(conv, g1_w, ip, jp);

    // 5. fused pair kernel (2 i's per block) -> partial sums
    k_pair<<<BATCH*32, 256, 0, stream>>>(qp, ip, jp, g2_w, g2_b, part);

    // 6. final MLP + log_softmax
    k_final<<<BATCH, 256, 0, stream>>>(part, f1_w, f1_b, f2_w, f2_b, out);
}